// Round 8
// baseline (103.897 us; speedup 1.0000x reference)
//
#include <hip/hip_runtime.h>

#define WIRE_DIM  32
#define NUM_WIRES 64
#define BATCH     8192
#define HID       10
#define STRIDE    36   // 32 + 4 pad: avoids the stride-32 single-bank disaster;
                       // rows stay 16B-aligned for b128

// broadcast-read a float from a wave-uniform lane index -> scalar
__device__ __forceinline__ float rl(float x, int slane) {
    return __uint_as_float(__builtin_amdgcn_readlane(__float_as_uint(x), slane));
}

__global__ __launch_bounds__(256) void isnet_kernel(
    const float* __restrict__ outputs,
    const int*   __restrict__ tests,
    const float* __restrict__ W1,
    const float* __restrict__ bias1,
    const float* __restrict__ W2,
    const float* __restrict__ bias2,
    float*       __restrict__ out)
{
    // wave-private staging: 4 waves x 64 rows x 36 floats = 36 KB/block
    __shared__ __align__(16) float stage[4][NUM_WIRES * STRIDE];

    const int tid  = threadIdx.x;
    const int lane = tid & 63;
    const int wave = tid >> 6;
    float* buf = stage[wave];

    const int b = blockIdx.x * 4 + wave;          // one batch per wave

    const int sp = __builtin_amdgcn_readfirstlane(tests[2 * b]);      // person
    const int sl = __builtin_amdgcn_readfirstlane(tests[2 * b + 1]);  // location

    // ---- stage coalesced: 8 x contiguous-1KB wave loads -> padded LDS ----
    const float* g = outputs + (size_t)b * (NUM_WIRES * WIRE_DIM) + lane * 4;
    const int r  = lane >> 3;                     // row-group within slab
    const int cc = lane & 7;                      // 16B chunk within row
    {
        float4 c[8];
        #pragma unroll
        for (int t = 0; t < 8; ++t) c[t] = *(const float4*)(g + t * 256);
        #pragma unroll
        for (int t = 0; t < 8; ++t)
            *(float4*)&buf[(t * 8 + r) * STRIDE + cc * 4] = c[t];
    }
    // wave-private buffer: no __syncthreads needed

    // ---- readback ONCE into registers: own wire row + person row ----
    // (R7 lesson: per-iteration ds_read + s_load share lgkmcnt -> 16 hard
    //  drains per wave; co-resident waves stall in lockstep. Hoist all
    //  vector-memory out of the loop; body becomes pure FMA.)
    float4 x[8], p[8];
    #pragma unroll
    for (int t = 0; t < 8; ++t)
        x[t] = *(const float4*)&buf[lane * STRIDE + t * 4];
    #pragma unroll
    for (int t = 0; t < 8; ++t)                   // uniform addr -> broadcast
        p[t] = *(const float4*)&buf[sp * STRIDE + t * 4];

    float acc[HID];
    #pragma unroll
    for (int h = 0; h < HID; ++h) acc[h] = bias1[h];   // uniform -> s_load

    // ---- fully-unrolled compute: zero vector loads in the body.
    // Safe to unroll (unlike R4): nothing to hoist but scalar loads;
    // live set = x(32) + p(32) + acc(10) + temps ~= 90 VGPR.
    #pragma unroll
    for (int j = 0; j < 8; ++j) {
        const float* wp = W1 + (4 * j) * HID;        // person rows 4j..4j+3
        const float* ww = W1 + (32 + 4 * j) * HID;   // wire rows 32+4j..
        #pragma unroll
        for (int h = 0; h < HID; ++h) {
            acc[h] += p[j].x * wp[0 * HID + h] + p[j].y * wp[1 * HID + h]
                    + p[j].z * wp[2 * HID + h] + p[j].w * wp[3 * HID + h]
                    + x[j].x * ww[0 * HID + h] + x[j].y * ww[1 * HID + h]
                    + x[j].z * ww[2 * HID + h] + x[j].w * ww[3 * HID + h];
        }
    }

    // ---- relu -> W2 -> logit per lane(=wire) -> wave softmax -> loss ----
    float v = bias2[0];
    #pragma unroll
    for (int h = 0; h < HID; ++h) v += fmaxf(acc[h], 0.f) * W2[h];

    float m = v;
    #pragma unroll
    for (int off = 32; off > 0; off >>= 1) m = fmaxf(m, __shfl_xor(m, off));
    float s = __expf(v - m);
    #pragma unroll
    for (int off = 32; off > 0; off >>= 1) s += __shfl_xor(s, off);
    float lv = rl(v, sl);                        // logit at `location`
    if (lane == 0) out[b] = m + __logf(s) - lv;  // -log_softmax[loc]
}

extern "C" void kernel_launch(void* const* d_in, const int* in_sizes, int n_in,
                              void* d_out, int out_size, void* d_ws, size_t ws_size,
                              hipStream_t stream) {
    const float* outputs = (const float*)d_in[0];
    const int*   tests   = (const int*)d_in[1];
    const float* W1      = (const float*)d_in[2];
    const float* b1      = (const float*)d_in[3];
    const float* W2      = (const float*)d_in[4];
    const float* b2      = (const float*)d_in[5];
    float* out = (float*)d_out;

    // 4 batches per block (4 waves x 1 batch) -> 2048 blocks
    isnet_kernel<<<BATCH / 4, 256, 0, stream>>>(
        outputs, tests, W1, b1, W2, b2, out);
}